// Round 1
// baseline (11993.578 us; speedup 1.0000x reference)
//
#include <hip/hip_runtime.h>
#include <cmath>

// Problem constants (from reference): L=128, B=256, H=256, C=17, Y=16, N_SUB=2
#define L_   128
#define B_   256
#define H_   256
#define C_   17
#define Y_   16
#define NSUB 254   // (L-1) * N_SUB substeps

// Workspace layout (fp32), all offsets 256B-aligned:
//   dXs  [254][B][C]   : dX * (h/2) folded                  (4,419,584 B)
//   zT   [H][B]        : current state, transposed          (262,144 B)
//   hdn4 [H/4][B][4]   : relu(z@W1+b1), packed for float4   (262,144 B)
//   W1T  [H][H]        : W1 transposed (W1T[h][k]=W1[k][h]) (262,144 B)
#define OFF_ZT   4419584
#define OFF_HDN  (4419584 + 262144)
#define OFF_W1T  (4419584 + 2*262144)

// ---------------------------------------------------------------------------
// Precompute dX*(h/2) for every (substep, b, c) from Hermite coefficients.
__global__ void k_dx(const float* __restrict__ ts, const float* __restrict__ us,
                     float* __restrict__ dXs) {
  int idx = blockIdx.x * 256 + threadIdx.x;
  if (idx >= NSUB * B_ * C_) return;
  int c   = idx % C_;
  int t2  = idx / C_;
  int b   = t2 & (B_ - 1);
  int sub = t2 >> 8;
  int s = sub >> 1, j = sub & 1;

  float t_s = ts[s * B_];
  float t_n = ts[(s + 1) * B_];
  float h = t_n - t_s;

  float xi, xn;
  if (c == 0) {
    xi = ts[s * B_ + b];
    xn = ts[(s + 1) * B_ + b];
  } else {
    xi = us[(size_t)s       * (B_ * 16) + b * 16 + (c - 1)];
    xn = us[(size_t)(s + 1) * (B_ * 16) + b * 16 + (c - 1)];
  }
  float mn = (xn - xi) / h;            // slope_s
  float mi;
  if (s == 0) {
    mi = mn;                           // m_0 = slope_0
  } else {
    float hp = t_s - ts[(s - 1) * B_];
    float xp = (c == 0) ? ts[(s - 1) * B_ + b]
                        : us[(size_t)(s - 1) * (B_ * 16) + b * 16 + (c - 1)];
    mi = (xi - xp) / hp;               // slope_{s-1}
  }
  float c2 = 3.f * (xn - xi) / (h * h) - (2.f * mi + mn) / h;
  float c3 = 2.f * (xi - xn) / (h * h * h) + (mi + mn) / (h * h);
  float u  = j ? 0.5f * h : 0.f;
  float dX = mi + 2.f * c2 * u + 3.f * c3 * u * u;
  dXs[idx] = dX * 0.5f * h;            // fold in the (h/N_SUB) step scale
}

// ---------------------------------------------------------------------------
// One-time transpose of W1 so k_hdn's weight row is contiguous for s_loads.
__global__ void k_tw1(const float* __restrict__ W1, float* __restrict__ W1T) {
  int i = blockIdx.x * 256 + threadIdx.x;   // 65536: k = i>>8, h = i&255
  W1T[(i & 255) * 256 + (i >> 8)] = W1[i];
}

// zT[h][b] = enc_b[h]  (z0 = 0@enc_W + enc_b = enc_b, broadcast over batch)
__global__ void k_init(const float* __restrict__ enc_b, float* __restrict__ zT) {
  int i = blockIdx.x * 256 + threadIdx.x;   // 65536
  zT[i] = enc_b[i >> 8];
}

// ---------------------------------------------------------------------------
// hdn = relu(z @ W1 + b1); on even substeps, ht==0 blocks also decode
// out[sub/2] = z @ dec_W + dec_b (z here is the state BEFORE this substep).
// Grid 256 = 4 b-tiles(64) x 64 h-tiles(4). Block 256 thr: lane=b, wave=h.
__global__ __launch_bounds__(256)
void k_hdn(const float* __restrict__ zT, const float* __restrict__ W1T,
           const float* __restrict__ b1, float* __restrict__ hdn4,
           const float* __restrict__ decW, const float* __restrict__ decb,
           float* __restrict__ out, int sub) {
  int bt = blockIdx.x & 3, ht = blockIdx.x >> 2;
  int lane = threadIdx.x & 63, hw = threadIdx.x >> 6;
  int bb = bt * 64 + lane;
  int hh = __builtin_amdgcn_readfirstlane(ht * 4 + hw);  // wave-uniform h
  const float* w1row = W1T + hh * 256;

  float acc = 0.f;
  bool dec = ((sub & 1) == 0) && (ht == 0);
  if (dec) {
    float a0 = 0.f, a1 = 0.f, a2 = 0.f, a3 = 0.f;
    const float* dwr = decW + hw * 4;       // wave-uniform y-range
    for (int k = 0; k < 256; ++k) {
      float zv = zT[k * 256 + bb];
      acc = fmaf(zv, w1row[k], acc);
      a0 = fmaf(zv, dwr[k * 16 + 0], a0);
      a1 = fmaf(zv, dwr[k * 16 + 1], a1);
      a2 = fmaf(zv, dwr[k * 16 + 2], a2);
      a3 = fmaf(zv, dwr[k * 16 + 3], a3);
    }
    int row = sub >> 1;
    float* op = out + (size_t)row * (B_ * Y_) + bb * Y_ + hw * 4;
    op[0] = a0 + decb[hw * 4 + 0];
    op[1] = a1 + decb[hw * 4 + 1];
    op[2] = a2 + decb[hw * 4 + 2];
    op[3] = a3 + decb[hw * 4 + 3];
  } else {
    #pragma unroll 4
    for (int k = 0; k < 256; ++k)
      acc = fmaf(zT[k * 256 + bb], w1row[k], acc);
  }
  float hv = fmaxf(acc + b1[hh], 0.f);
  // packed layout for k_upd's float4 A-loads: hdn4[h>>2][b][h&3]
  hdn4[(hh >> 2) * (B_ * 4) + bb * 4 + (hh & 3)] = hv;
}

// ---------------------------------------------------------------------------
// z[b,h] += sum_c tanh(hdn[b,:]@W2[:,h*17+c] + b2[h*17+c]) * dXs[sub,b,c]
// Grid 512 = 4 b-tiles(64) x 128 h-tiles(2). Block 128 thr: lane=b, wave=h.
// A from hdn4 as coalesced float4; W2 row segment wave-uniform -> s_loads.
__global__ __launch_bounds__(128)
void k_upd(const float* __restrict__ hdn4, const float* __restrict__ W2,
           const float* __restrict__ b2, const float* __restrict__ dXs,
           float* __restrict__ zT, int sub) {
  int bt = blockIdx.x & 3, ht = blockIdx.x >> 2;   // ht 0..127
  int lane = threadIdx.x & 63, hw = threadIdx.x >> 6;  // hw 0..1
  int bb = bt * 64 + lane;
  int h = ht * 2 + hw;
  int col = __builtin_amdgcn_readfirstlane(h * C_);  // wave-uniform col base

  float acc[C_];
  #pragma unroll
  for (int c = 0; c < C_; ++c) acc[c] = 0.f;

  const float4* hp = (const float4*)hdn4 + bb;   // element (k>>2)*256 + bb
  for (int k4 = 0; k4 < 64; ++k4) {
    float4 a4 = hp[(size_t)k4 * 256];
    const float* w = W2 + (size_t)(k4 * 4) * (H_ * C_) + col;
    #pragma unroll
    for (int c = 0; c < C_; ++c) acc[c] = fmaf(a4.x, w[c], acc[c]);
    w += H_ * C_;
    #pragma unroll
    for (int c = 0; c < C_; ++c) acc[c] = fmaf(a4.y, w[c], acc[c]);
    w += H_ * C_;
    #pragma unroll
    for (int c = 0; c < C_; ++c) acc[c] = fmaf(a4.z, w[c], acc[c]);
    w += H_ * C_;
    #pragma unroll
    for (int c = 0; c < C_; ++c) acc[c] = fmaf(a4.w, w[c], acc[c]);
  }

  float gz = 0.f;
  const float* dxp = dXs + (size_t)sub * (B_ * C_) + bb * C_;
  const float* b2p = b2 + col;
  #pragma unroll
  for (int c = 0; c < C_; ++c) {
    float g = tanhf(acc[c] + b2p[c]);
    gz = fmaf(g, dxp[c], gz);
  }
  zT[h * 256 + bb] += gz;
}

// ---------------------------------------------------------------------------
// Final decode: out[127] = z @ dec_W + dec_b
__global__ __launch_bounds__(256)
void k_fin(const float* __restrict__ zT, const float* __restrict__ decW,
           const float* __restrict__ decb, float* __restrict__ out) {
  int bt = blockIdx.x;
  int lane = threadIdx.x & 63, hw = threadIdx.x >> 6;
  int bb = bt * 64 + lane;
  float a0 = 0.f, a1 = 0.f, a2 = 0.f, a3 = 0.f;
  const float* dwr = decW + hw * 4;
  for (int k = 0; k < 256; ++k) {
    float zv = zT[k * 256 + bb];
    a0 = fmaf(zv, dwr[k * 16 + 0], a0);
    a1 = fmaf(zv, dwr[k * 16 + 1], a1);
    a2 = fmaf(zv, dwr[k * 16 + 2], a2);
    a3 = fmaf(zv, dwr[k * 16 + 3], a3);
  }
  float* op = out + (size_t)(L_ - 1) * (B_ * Y_) + bb * Y_ + hw * 4;
  op[0] = a0 + decb[hw * 4 + 0];
  op[1] = a1 + decb[hw * 4 + 1];
  op[2] = a2 + decb[hw * 4 + 2];
  op[3] = a3 + decb[hw * 4 + 3];
}

// ---------------------------------------------------------------------------
extern "C" void kernel_launch(void* const* d_in, const int* in_sizes, int n_in,
                              void* d_out, int out_size, void* d_ws, size_t ws_size,
                              hipStream_t stream) {
  const float* ts    = (const float*)d_in[0];
  const float* us    = (const float*)d_in[1];
  // d_in[2] ys: unused; d_in[3] batch_size: fixed 256; d_in[4] enc_W: z0=enc_b
  const float* enc_b = (const float*)d_in[5];
  const float* dec_W = (const float*)d_in[6];
  const float* dec_b = (const float*)d_in[7];
  const float* f_W1  = (const float*)d_in[8];
  const float* f_b1  = (const float*)d_in[9];
  const float* f_W2  = (const float*)d_in[10];
  const float* f_b2  = (const float*)d_in[11];
  float* out = (float*)d_out;

  char* ws = (char*)d_ws;
  float* dXs  = (float*)(ws);
  float* zT   = (float*)(ws + OFF_ZT);
  float* hdn4 = (float*)(ws + OFF_HDN);
  float* W1T  = (float*)(ws + OFF_W1T);

  k_dx  <<<(NSUB * B_ * C_ + 255) / 256, 256, 0, stream>>>(ts, us, dXs);
  k_tw1 <<<256, 256, 0, stream>>>(f_W1, W1T);
  k_init<<<256, 256, 0, stream>>>(enc_b, zT);

  for (int sub = 0; sub < NSUB; ++sub) {
    k_hdn<<<256, 256, 0, stream>>>(zT, W1T, f_b1, hdn4, dec_W, dec_b, out, sub);
    k_upd<<<512, 128, 0, stream>>>(hdn4, f_W2, f_b2, dXs, zT, sub);
  }
  k_fin<<<4, 256, 0, stream>>>(zT, dec_W, dec_b, out);
}

// Round 2
// 7668.893 us; speedup vs baseline: 1.5639x; 1.5639x over previous
//
#include <hip/hip_runtime.h>
#include <cmath>

// Problem constants (from reference): L=128, B=256, H=256, C=17, Y=16, N_SUB=2
#define L_   128
#define B_   256
#define H_   256
#define C_   17
#define Y_   16
#define NSUB 254   // (L-1) * N_SUB substeps

// Workspace layout (fp32), all offsets 256B-aligned:
//   dXs  [254][B][C]   : dX * (h/2) folded                  (4,419,584 B)
//   zT   [H][B]        : current state, transposed          (262,144 B)
//   hdn4 [H/4][B][4]   : relu(z@W1+b1), packed for float4   (262,144 B)
//   W1T  [H][H]        : W1 transposed (W1T[h][k]=W1[k][h]) (262,144 B)
#define OFF_ZT   4419584
#define OFF_HDN  (4419584 + 262144)
#define OFF_W1T  (4419584 + 2*262144)

__device__ __forceinline__ float fast_tanh(float x) {
  // tanh(x) = 1 - 2/(e^{2x}+1); saturates correctly for |x| large.
  float e = __expf(2.0f * x);
  return 1.0f - __fdividef(2.0f, e + 1.0f);
}

// ---------------------------------------------------------------------------
// Precompute dX*(h/2) for every (substep, b, c) from Hermite coefficients.
__global__ void k_dx(const float* __restrict__ ts, const float* __restrict__ us,
                     float* __restrict__ dXs) {
  int idx = blockIdx.x * 256 + threadIdx.x;
  if (idx >= NSUB * B_ * C_) return;
  int c   = idx % C_;
  int t2  = idx / C_;
  int b   = t2 & (B_ - 1);
  int sub = t2 >> 8;
  int s = sub >> 1, j = sub & 1;

  float t_s = ts[s * B_];
  float t_n = ts[(s + 1) * B_];
  float h = t_n - t_s;

  float xi, xn;
  if (c == 0) {
    xi = ts[s * B_ + b];
    xn = ts[(s + 1) * B_ + b];
  } else {
    xi = us[(size_t)s       * (B_ * 16) + b * 16 + (c - 1)];
    xn = us[(size_t)(s + 1) * (B_ * 16) + b * 16 + (c - 1)];
  }
  float mn = (xn - xi) / h;            // slope_s
  float mi;
  if (s == 0) {
    mi = mn;                           // m_0 = slope_0
  } else {
    float hp = t_s - ts[(s - 1) * B_];
    float xp = (c == 0) ? ts[(s - 1) * B_ + b]
                        : us[(size_t)(s - 1) * (B_ * 16) + b * 16 + (c - 1)];
    mi = (xi - xp) / hp;               // slope_{s-1}
  }
  float c2 = 3.f * (xn - xi) / (h * h) - (2.f * mi + mn) / h;
  float c3 = 2.f * (xi - xn) / (h * h * h) + (mi + mn) / (h * h);
  float u  = j ? 0.5f * h : 0.f;
  float dX = mi + 2.f * c2 * u + 3.f * c3 * u * u;
  dXs[idx] = dX * 0.5f * h;            // fold in the (h/N_SUB) step scale
}

// ---------------------------------------------------------------------------
// One-time transpose of W1 so k_hdn's weight row is contiguous for s_loads.
__global__ void k_tw1(const float* __restrict__ W1, float* __restrict__ W1T) {
  int i = blockIdx.x * 256 + threadIdx.x;   // 65536: k = i>>8, h = i&255
  W1T[(i & 255) * 256 + (i >> 8)] = W1[i];
}

// zT[h][b] = enc_b[h]  (z0 = 0@enc_W + enc_b = enc_b, broadcast over batch)
__global__ void k_init(const float* __restrict__ enc_b, float* __restrict__ zT) {
  int i = blockIdx.x * 256 + threadIdx.x;   // 65536
  zT[i] = enc_b[i >> 8];
}

// ---------------------------------------------------------------------------
// GEMM1: hdn = relu(z @ W1 + b1), K-split x4.
// Blocks 0..1023: (bt = blk&3, h = blk>>2). 4 waves = 4 K-quarters, lane = b.
// Blocks 1024..1039 (even sub only): decode out[sub/2] = z @ dec_W + dec_b;
//   block = y (16), thread = b (256).
__global__ __launch_bounds__(256)
void k_hdn(const float* __restrict__ zT, const float* __restrict__ W1T,
           const float* __restrict__ b1, float* __restrict__ hdn4,
           const float* __restrict__ decW, const float* __restrict__ decb,
           float* __restrict__ out, int sub) {
  __shared__ float red[3][64];
  if (blockIdx.x < 1024) {
    int bt = blockIdx.x & 3, h = blockIdx.x >> 2;
    int lane = threadIdx.x & 63;
    int w = __builtin_amdgcn_readfirstlane(threadIdx.x >> 6);   // K-quarter
    int bb = bt * 64 + lane;
    const float* w1p = W1T + h * 256 + w * 64;   // wave-uniform
    const float* zp  = zT + (size_t)(w * 64) * 256 + bb;
    float a0 = 0.f, a1 = 0.f, a2 = 0.f, a3 = 0.f;
    #pragma unroll
    for (int k = 0; k < 64; k += 4) {
      a0 = fmaf(zp[(k + 0) * 256], w1p[k + 0], a0);
      a1 = fmaf(zp[(k + 1) * 256], w1p[k + 1], a1);
      a2 = fmaf(zp[(k + 2) * 256], w1p[k + 2], a2);
      a3 = fmaf(zp[(k + 3) * 256], w1p[k + 3], a3);
    }
    float acc = (a0 + a1) + (a2 + a3);
    if (w) red[w - 1][lane] = acc;
    __syncthreads();
    if (w == 0) {
      acc += red[0][lane] + red[1][lane] + red[2][lane];
      float hv = fmaxf(acc + b1[h], 0.f);
      hdn4[(h >> 2) * (B_ * 4) + bb * 4 + (h & 3)] = hv;
    }
  } else if ((sub & 1) == 0) {
    int y = blockIdx.x - 1024;          // 0..15, block-uniform
    int b = threadIdx.x;
    const float* dwp = decW + y;
    float a0 = 0.f, a1 = 0.f, a2 = 0.f, a3 = 0.f;
    #pragma unroll 4
    for (int k = 0; k < 256; k += 4) {
      a0 = fmaf(zT[(k + 0) * 256 + b], dwp[(k + 0) * 16], a0);
      a1 = fmaf(zT[(k + 1) * 256 + b], dwp[(k + 1) * 16], a1);
      a2 = fmaf(zT[(k + 2) * 256 + b], dwp[(k + 2) * 16], a2);
      a3 = fmaf(zT[(k + 3) * 256 + b], dwp[(k + 3) * 16], a3);
    }
    out[(size_t)(sub >> 1) * (B_ * Y_) + b * Y_ + y] =
        (a0 + a1) + (a2 + a3) + decb[y];
  }
}

// ---------------------------------------------------------------------------
// GEMM2 + tanh + c-contraction + z update, K-split x4.
// Grid 1024 = (bt = blk&3, h = blk>>2). 4 waves = 4 K-quarters, lane = b.
// Never materializes the (B,H,C) tensor.
__global__ __launch_bounds__(256)
void k_upd(const float* __restrict__ hdn4, const float* __restrict__ W2,
           const float* __restrict__ b2, const float* __restrict__ dXs,
           float* __restrict__ zT, int sub) {
  __shared__ float red[3][64][C_];   // 12.75 KB
  int bt = blockIdx.x & 3, h = blockIdx.x >> 2;
  int lane = threadIdx.x & 63;
  int w = __builtin_amdgcn_readfirstlane(threadIdx.x >> 6);   // K-quarter
  int bb = bt * 64 + lane;
  int col = __builtin_amdgcn_readfirstlane(h * C_);

  float acc[C_];
  #pragma unroll
  for (int c = 0; c < C_; ++c) acc[c] = 0.f;

  // hdn4 packed [k/4][b][4]: float4 per (k-group, b). This wave's quarter:
  const float4* hp = (const float4*)hdn4 + bb + (size_t)(w * 16) * 256;
  const float* wbase = W2 + (size_t)(w * 64) * (H_ * C_) + col;  // uniform
  #pragma unroll 4
  for (int k4 = 0; k4 < 16; ++k4) {
    float4 a4 = hp[(size_t)k4 * 256];
    const float* wp = wbase + (size_t)(k4 * 4) * (H_ * C_);
    #pragma unroll
    for (int c = 0; c < C_; ++c) acc[c] = fmaf(a4.x, wp[c], acc[c]);
    wp += H_ * C_;
    #pragma unroll
    for (int c = 0; c < C_; ++c) acc[c] = fmaf(a4.y, wp[c], acc[c]);
    wp += H_ * C_;
    #pragma unroll
    for (int c = 0; c < C_; ++c) acc[c] = fmaf(a4.z, wp[c], acc[c]);
    wp += H_ * C_;
    #pragma unroll
    for (int c = 0; c < C_; ++c) acc[c] = fmaf(a4.w, wp[c], acc[c]);
  }

  if (w) {
    #pragma unroll
    for (int c = 0; c < C_; ++c) red[w - 1][lane][c] = acc[c];
  }
  __syncthreads();
  if (w == 0) {
    #pragma unroll
    for (int c = 0; c < C_; ++c)
      acc[c] += red[0][lane][c] + (red[1][lane][c] + red[2][lane][c]);
    float gz = 0.f;
    const float* dxp = dXs + (size_t)sub * (B_ * C_) + bb * C_;
    const float* b2p = b2 + col;
    #pragma unroll
    for (int c = 0; c < C_; ++c) {
      float g = fast_tanh(acc[c] + b2p[c]);
      gz = fmaf(g, dxp[c], gz);
    }
    zT[h * 256 + bb] += gz;
  }
}

// ---------------------------------------------------------------------------
// Final decode: out[127] = z @ dec_W + dec_b
__global__ __launch_bounds__(256)
void k_fin(const float* __restrict__ zT, const float* __restrict__ decW,
           const float* __restrict__ decb, float* __restrict__ out) {
  int bt = blockIdx.x;
  int lane = threadIdx.x & 63, hw = threadIdx.x >> 6;
  int bb = bt * 64 + lane;
  float a0 = 0.f, a1 = 0.f, a2 = 0.f, a3 = 0.f;
  const float* dwr = decW + hw * 4;
  for (int k = 0; k < 256; ++k) {
    float zv = zT[k * 256 + bb];
    a0 = fmaf(zv, dwr[k * 16 + 0], a0);
    a1 = fmaf(zv, dwr[k * 16 + 1], a1);
    a2 = fmaf(zv, dwr[k * 16 + 2], a2);
    a3 = fmaf(zv, dwr[k * 16 + 3], a3);
  }
  float* op = out + (size_t)(L_ - 1) * (B_ * Y_) + bb * Y_ + hw * 4;
  op[0] = a0 + decb[hw * 4 + 0];
  op[1] = a1 + decb[hw * 4 + 1];
  op[2] = a2 + decb[hw * 4 + 2];
  op[3] = a3 + decb[hw * 4 + 3];
}

// ---------------------------------------------------------------------------
extern "C" void kernel_launch(void* const* d_in, const int* in_sizes, int n_in,
                              void* d_out, int out_size, void* d_ws, size_t ws_size,
                              hipStream_t stream) {
  const float* ts    = (const float*)d_in[0];
  const float* us    = (const float*)d_in[1];
  // d_in[2] ys: unused; d_in[3] batch_size: fixed 256; d_in[4] enc_W: z0=enc_b
  const float* enc_b = (const float*)d_in[5];
  const float* dec_W = (const float*)d_in[6];
  const float* dec_b = (const float*)d_in[7];
  const float* f_W1  = (const float*)d_in[8];
  const float* f_b1  = (const float*)d_in[9];
  const float* f_W2  = (const float*)d_in[10];
  const float* f_b2  = (const float*)d_in[11];
  float* out = (float*)d_out;

  char* ws = (char*)d_ws;
  float* dXs  = (float*)(ws);
  float* zT   = (float*)(ws + OFF_ZT);
  float* hdn4 = (float*)(ws + OFF_HDN);
  float* W1T  = (float*)(ws + OFF_W1T);

  k_dx  <<<(NSUB * B_ * C_ + 255) / 256, 256, 0, stream>>>(ts, us, dXs);
  k_tw1 <<<256, 256, 0, stream>>>(f_W1, W1T);
  k_init<<<256, 256, 0, stream>>>(enc_b, zT);

  for (int sub = 0; sub < NSUB; ++sub) {
    k_hdn<<<1040, 256, 0, stream>>>(zT, W1T, f_b1, hdn4, dec_W, dec_b, out, sub);
    k_upd<<<1024, 256, 0, stream>>>(hdn4, f_W2, f_b2, dXs, zT, sub);
  }
  k_fin<<<4, 256, 0, stream>>>(zT, dec_W, dec_b, out);
}

// Round 3
// 7233.777 us; speedup vs baseline: 1.6580x; 1.0602x over previous
//
#include <hip/hip_runtime.h>
#include <cmath>

// Problem constants: L=128, B=256, H=256, C=17, Y=16, N_SUB=2
#define L_   128
#define B_   256
#define H_   256
#define C_   17
#define Y_   16
#define NSUB 254   // (L-1) * N_SUB

// Workspace layout (float offsets):
//  dXsT [254][17][256] : dX * (h/2), c-major for coalesced tail reads
//  zT   [256h][256b]   : state, transposed
//  hdn4 [64][256b][4]  : relu(z@W1+b1), packed [k/4][b][k%4]
//  W1R  [64][256h][4]  : W1 re-tiled per k-quad (bcast float4 per h)
//  W2P  [256h][5140]   : per-h weight block: [k=0..255][c=0..19 pad] + b2 row
#define NDXF     (NSUB * 4352)                 // 1,105,408
#define OFF_ZT   NDXF
#define OFF_HDN  (OFF_ZT + 65536)
#define OFF_W1R  (OFF_HDN + 65536)
#define OFF_W2P  (OFF_W1R + 65536)
#define W2P_H    5140                          // 257 rows * 20, 16B-aligned

__device__ __forceinline__ float fast_tanh(float x) {
  float e = __expf(2.0f * x);
  return 1.0f - __fdividef(2.0f, e + 1.0f);
}

// ---------------------------------------------------------------------------
// dXsT[sub][c][b] = dX * (h/2)
__global__ void k_dx(const float* __restrict__ ts, const float* __restrict__ us,
                     float* __restrict__ dXsT) {
  int idx = blockIdx.x * 256 + threadIdx.x;
  if (idx >= NSUB * B_ * C_) return;
  int c   = idx % C_;
  int t2  = idx / C_;
  int b   = t2 & (B_ - 1);
  int sub = t2 >> 8;
  int s = sub >> 1, j = sub & 1;

  float t_s = ts[s * B_];
  float t_n = ts[(s + 1) * B_];
  float h = t_n - t_s;

  float xi, xn;
  if (c == 0) {
    xi = ts[s * B_ + b];
    xn = ts[(s + 1) * B_ + b];
  } else {
    xi = us[(size_t)s       * (B_ * 16) + b * 16 + (c - 1)];
    xn = us[(size_t)(s + 1) * (B_ * 16) + b * 16 + (c - 1)];
  }
  float mn = (xn - xi) / h;
  float mi;
  if (s == 0) {
    mi = mn;
  } else {
    float hp = t_s - ts[(s - 1) * B_];
    float xp = (c == 0) ? ts[(s - 1) * B_ + b]
                        : us[(size_t)(s - 1) * (B_ * 16) + b * 16 + (c - 1)];
    mi = (xi - xp) / hp;
  }
  float c2 = 3.f * (xn - xi) / (h * h) - (2.f * mi + mn) / h;
  float c3 = 2.f * (xi - xn) / (h * h * h) + (mi + mn) / (h * h);
  float u  = j ? 0.5f * h : 0.f;
  float dX = mi + 2.f * c2 * u + 3.f * c3 * u * u;
  dXsT[(size_t)sub * 4352 + c * 256 + b] = dX * 0.5f * h;
}

// ---------------------------------------------------------------------------
// W1R[kt][h][kk] = W1[h][kt*4+kk]   (one-time re-tile)
__global__ void k_w1r(const float* __restrict__ W1, float* __restrict__ W1R) {
  int i = blockIdx.x * 256 + threadIdx.x;     // 65536
  int kt = i >> 10, h = (i >> 2) & 255, kk = i & 3;
  W1R[i] = W1[h * 256 + kt * 4 + kk];
}

// W2P[h][k*20+c] = W2[k][h*17+c] (c<17, else 0); row k=256 holds b2[h*17+c].
__global__ void k_w2p(const float* __restrict__ W2, const float* __restrict__ b2,
                      float* __restrict__ W2P) {
  int h = blockIdx.x;
  float* dst = W2P + (size_t)h * W2P_H;
  for (int i = threadIdx.x; i < W2P_H; i += 256) {
    int k = i / 20, c = i - k * 20;
    float v = 0.f;
    if (c < 17) {
      v = (k < 256) ? W2[(size_t)k * (H_ * C_) + h * 17 + c]
                    : b2[h * 17 + c];
    }
    dst[i] = v;
  }
}

// zT[h][b] = enc_b[h]
__global__ void k_init(const float* __restrict__ enc_b, float* __restrict__ zT) {
  int i = blockIdx.x * 256 + threadIdx.x;
  zT[i] = enc_b[i >> 8];
}

// ---------------------------------------------------------------------------
// GEMM1: hdn4 = relu(z @ W1 + b1).
// Blocks 0..255: (bq = blk&3 -> 64 b, kt = blk>>2 -> 4 k). 512 thr:
//   lane = b, wave w = h-eighth (32 h). Weights: 1 bcast float4 / h.
// Blocks 256..263 (even sub): decode out[sub/2]; block = 32 b, thr = (b,y).
__global__ __launch_bounds__(512)
void k_hdn(const float* __restrict__ zT, const float* __restrict__ W1R,
           const float* __restrict__ b1, float* __restrict__ hdn4,
           const float* __restrict__ decW, const float* __restrict__ decb,
           float* __restrict__ out, int sub) {
  __shared__ float4 red4[7][64];
  if (blockIdx.x < 256) {
    int bq = blockIdx.x & 3, kt = blockIdx.x >> 2;
    int lane = threadIdx.x & 63;
    int w = threadIdx.x >> 6;                  // h-eighth
    int bb = bq * 64 + lane;
    const float4* wr = (const float4*)(W1R + kt * 1024) + w * 32;
    const float*  zp = zT + (size_t)(w * 32) * 256 + bb;
    float a0 = 0.f, a1 = 0.f, a2 = 0.f, a3 = 0.f;
    #pragma unroll 4
    for (int i = 0; i < 32; ++i) {
      float zv = zp[i * 256];
      float4 wf = wr[i];
      a0 = fmaf(zv, wf.x, a0);
      a1 = fmaf(zv, wf.y, a1);
      a2 = fmaf(zv, wf.z, a2);
      a3 = fmaf(zv, wf.w, a3);
    }
    if (w) red4[w - 1][lane] = make_float4(a0, a1, a2, a3);
    __syncthreads();
    if (w == 0) {
      #pragma unroll
      for (int j = 0; j < 7; ++j) {
        float4 r = red4[j][lane];
        a0 += r.x; a1 += r.y; a2 += r.z; a3 += r.w;
      }
      float4 bv = *(const float4*)(b1 + kt * 4);
      float4 hv = make_float4(fmaxf(a0 + bv.x, 0.f), fmaxf(a1 + bv.y, 0.f),
                              fmaxf(a2 + bv.z, 0.f), fmaxf(a3 + bv.w, 0.f));
      *((float4*)hdn4 + kt * 256 + bb) = hv;
    }
  } else if ((sub & 1) == 0) {
    int d = blockIdx.x - 256;                  // 0..7 -> 32 b each
    int b = d * 32 + (threadIdx.x >> 4);
    int y = threadIdx.x & 15;
    float acc = 0.f;
    #pragma unroll 4
    for (int h = 0; h < 256; ++h)
      acc = fmaf(zT[h * 256 + b], decW[h * 16 + y], acc);
    out[(size_t)(sub >> 1) * (B_ * Y_) + b * Y_ + y] = acc + decb[y];
  }
}

// ---------------------------------------------------------------------------
// GEMM2 + tanh + c-contract + z update. Grid 512 = (bh = blk&1, h = blk>>1).
// 256 thr: lane = b (2 b's: +0/+64 within half), wave w = k-quarter.
// Weights from LDS via 5 broadcast ds_read_b128 per k -> 34 FMA per k.
__global__ __launch_bounds__(256)
void k_upd(const float* __restrict__ hdn4, const float* __restrict__ W2P,
           const float* __restrict__ dXsT, float* __restrict__ zT, int sub) {
  __shared__ float lw[W2P_H];                  // 20.56 KB
  __shared__ float red[3][64][34];             // 26.1 KB
  int bh = blockIdx.x & 1, h = blockIdx.x >> 1;
  int lane = threadIdx.x & 63;
  int w = threadIdx.x >> 6;                    // k-quarter

  // stage this h's weight block (contiguous) into LDS
  {
    const float4* src = (const float4*)(W2P + (size_t)h * W2P_H);
    float4* dst = (float4*)lw;
    for (int i = threadIdx.x; i < W2P_H / 4; i += 256) dst[i] = src[i];
  }
  __syncthreads();

  int b0 = bh * 128 + lane;                    // and b1 = b0 + 64
  float accA[17], accB[17];
  #pragma unroll
  for (int c = 0; c < 17; ++c) { accA[c] = 0.f; accB[c] = 0.f; }

  const float4* hp = (const float4*)hdn4 + (size_t)(w * 16) * 256;
  const float4* lw4 = (const float4*)lw;

  for (int k4 = 0; k4 < 16; ++k4) {
    float4 ha = hp[k4 * 256 + b0];
    float4 hb = hp[k4 * 256 + b0 + 64];
    int kb = (w * 64 + k4 * 4) * 5;
    #pragma unroll
    for (int kk = 0; kk < 4; ++kk) {
      float4 A = lw4[kb + kk * 5 + 0];
      float4 Bv = lw4[kb + kk * 5 + 1];
      float4 Cv = lw4[kb + kk * 5 + 2];
      float4 Dv = lw4[kb + kk * 5 + 3];
      float4 Ev = lw4[kb + kk * 5 + 4];
      float sa = (kk == 0) ? ha.x : (kk == 1) ? ha.y : (kk == 2) ? ha.z : ha.w;
      float sb = (kk == 0) ? hb.x : (kk == 1) ? hb.y : (kk == 2) ? hb.z : hb.w;
      accA[0]  = fmaf(sa, A.x,  accA[0]);  accB[0]  = fmaf(sb, A.x,  accB[0]);
      accA[1]  = fmaf(sa, A.y,  accA[1]);  accB[1]  = fmaf(sb, A.y,  accB[1]);
      accA[2]  = fmaf(sa, A.z,  accA[2]);  accB[2]  = fmaf(sb, A.z,  accB[2]);
      accA[3]  = fmaf(sa, A.w,  accA[3]);  accB[3]  = fmaf(sb, A.w,  accB[3]);
      accA[4]  = fmaf(sa, Bv.x, accA[4]);  accB[4]  = fmaf(sb, Bv.x, accB[4]);
      accA[5]  = fmaf(sa, Bv.y, accA[5]);  accB[5]  = fmaf(sb, Bv.y, accB[5]);
      accA[6]  = fmaf(sa, Bv.z, accA[6]);  accB[6]  = fmaf(sb, Bv.z, accB[6]);
      accA[7]  = fmaf(sa, Bv.w, accA[7]);  accB[7]  = fmaf(sb, Bv.w, accB[7]);
      accA[8]  = fmaf(sa, Cv.x, accA[8]);  accB[8]  = fmaf(sb, Cv.x, accB[8]);
      accA[9]  = fmaf(sa, Cv.y, accA[9]);  accB[9]  = fmaf(sb, Cv.y, accB[9]);
      accA[10] = fmaf(sa, Cv.z, accA[10]); accB[10] = fmaf(sb, Cv.z, accB[10]);
      accA[11] = fmaf(sa, Cv.w, accA[11]); accB[11] = fmaf(sb, Cv.w, accB[11]);
      accA[12] = fmaf(sa, Dv.x, accA[12]); accB[12] = fmaf(sb, Dv.x, accB[12]);
      accA[13] = fmaf(sa, Dv.y, accA[13]); accB[13] = fmaf(sb, Dv.y, accB[13]);
      accA[14] = fmaf(sa, Dv.z, accA[14]); accB[14] = fmaf(sb, Dv.z, accB[14]);
      accA[15] = fmaf(sa, Dv.w, accA[15]); accB[15] = fmaf(sb, Dv.w, accB[15]);
      accA[16] = fmaf(sa, Ev.x, accA[16]); accB[16] = fmaf(sb, Ev.x, accB[16]);
    }
  }

  if (w) {
    #pragma unroll
    for (int c = 0; c < 17; ++c) {
      red[w - 1][lane][c]      = accA[c];
      red[w - 1][lane][17 + c] = accB[c];
    }
  }
  __syncthreads();
  if (w == 0) {
    #pragma unroll
    for (int c = 0; c < 17; ++c) {
      accA[c] += red[0][lane][c] + (red[1][lane][c] + red[2][lane][c]);
      accB[c] += red[0][lane][17 + c] + (red[1][lane][17 + c] + red[2][lane][17 + c]);
    }
    float gzA = 0.f, gzB = 0.f;
    const float* dxp = dXsT + (size_t)sub * 4352;
    #pragma unroll
    for (int c = 0; c < 17; ++c) {
      float bc = lw[5120 + c];                 // b2 row
      float gA = fast_tanh(accA[c] + bc);
      float gB = fast_tanh(accB[c] + bc);
      gzA = fmaf(gA, dxp[c * 256 + b0], gzA);
      gzB = fmaf(gB, dxp[c * 256 + b0 + 64], gzB);
    }
    zT[h * 256 + b0]      += gzA;
    zT[h * 256 + b0 + 64] += gzB;
  }
}

// ---------------------------------------------------------------------------
// Final decode row 127. 8 blocks x 512 thr, thread = (b, y).
__global__ __launch_bounds__(512)
void k_fin(const float* __restrict__ zT, const float* __restrict__ decW,
           const float* __restrict__ decb, float* __restrict__ out) {
  int b = blockIdx.x * 32 + (threadIdx.x >> 4);
  int y = threadIdx.x & 15;
  float acc = 0.f;
  #pragma unroll 4
  for (int h = 0; h < 256; ++h)
    acc = fmaf(zT[h * 256 + b], decW[h * 16 + y], acc);
  out[(size_t)(L_ - 1) * (B_ * Y_) + b * Y_ + y] = acc + decb[y];
}

// ---------------------------------------------------------------------------
extern "C" void kernel_launch(void* const* d_in, const int* in_sizes, int n_in,
                              void* d_out, int out_size, void* d_ws, size_t ws_size,
                              hipStream_t stream) {
  const float* ts    = (const float*)d_in[0];
  const float* us    = (const float*)d_in[1];
  const float* enc_b = (const float*)d_in[5];
  const float* dec_W = (const float*)d_in[6];
  const float* dec_b = (const float*)d_in[7];
  const float* f_W1  = (const float*)d_in[8];
  const float* f_b1  = (const float*)d_in[9];
  const float* f_W2  = (const float*)d_in[10];
  const float* f_b2  = (const float*)d_in[11];
  float* out = (float*)d_out;

  float* ws   = (float*)d_ws;
  float* dXsT = ws;
  float* zT   = ws + OFF_ZT;
  float* hdn4 = ws + OFF_HDN;
  float* W1R  = ws + OFF_W1R;
  float* W2P  = ws + OFF_W2P;

  k_dx  <<<(NSUB * B_ * C_ + 255) / 256, 256, 0, stream>>>(ts, us, dXsT);
  k_w1r <<<256, 256, 0, stream>>>(f_W1, W1R);
  k_w2p <<<256, 256, 0, stream>>>(f_W2, f_b2, W2P);
  k_init<<<256, 256, 0, stream>>>(enc_b, zT);

  for (int sub = 0; sub < NSUB; ++sub) {
    int hb = ((sub & 1) == 0) ? 264 : 256;     // decode blocks on even subs
    k_hdn<<<hb, 512, 0, stream>>>(zT, W1R, f_b1, hdn4, dec_W, dec_b, out, sub);
    k_upd<<<512, 256, 0, stream>>>(hdn4, W2P, dXsT, zT, sub);
  }
  k_fin<<<8, 512, 0, stream>>>(zT, dec_W, dec_b, out);
}